// Round 15
// baseline (833.216 us; speedup 1.0000x reference)
//
#include <hip/hip_runtime.h>

#define QD 256   // states
#define SD 128   // symbols
#define BD 1024  // batch
#define TD 128   // time steps
// P rows stored as 64 SELF-VALIDATING u64 words: lo32 = 4 fp8 e4m3 payload bytes
// (stored byte p = P''[state p], identity stored space), hi32 = exact step tag.
// P''_1 = 2^-1 * P_1 (first transition folded); steps t=1..127:
// P'' <- (P'' @ exp(A)/4) * 2^-6 => *2^-8/step. out = log(sum P'' e^final) + 1017*ln2.
//
// THIS REVISION: r14 + SAFE depth-2 pipelined poll. r14 (regular launches +
// manual barrier) confirmed launch overhead: 683->645us, dispatch 585us.
// Hop budget: 4.4us = compute 0.3 + visibility ~0.5 + DETECT (~0.34us poll
// period -> ~0.6-0.7us visible-but-undetected, max-amplified over 16 rows).
// New spin: two named reg sets A/B, >=1 always in flight; check only the set
// proven complete by vmcnt(8) (vmcnt retires in issue order); EVERY exit path
// runs vmcnt(0) with BOTH sets as asm operands (keeps regs live through the
// drain -> closes r7's reuse hole). Sampling period ~= check time. Gated
// first-tiles (depth<TD fallback only) keep the r14 single-set spin verbatim.
// Everything else byte-identical to r14.

typedef float floatx4 __attribute__((ext_vector_type(4)));
typedef unsigned uintx4 __attribute__((ext_vector_type(4)));
typedef unsigned long long u64;

#define ISSUE8 \
  "global_load_dwordx4 %0, %8, off sc0 sc1\n\t" \
  "global_load_dwordx4 %1, %8, off offset:64 sc0 sc1\n\t" \
  "global_load_dwordx4 %2, %8, off offset:128 sc0 sc1\n\t" \
  "global_load_dwordx4 %3, %8, off offset:192 sc0 sc1\n\t" \
  "global_load_dwordx4 %4, %8, off offset:256 sc0 sc1\n\t" \
  "global_load_dwordx4 %5, %8, off offset:320 sc0 sc1\n\t" \
  "global_load_dwordx4 %6, %8, off offset:384 sc0 sc1\n\t" \
  "global_load_dwordx4 %7, %8, off offset:448 sc0 sc1"

#define OUTS(c) "=&v"(c[0]), "=&v"(c[1]), "=&v"(c[2]), "=&v"(c[3]), \
                "=&v"(c[4]), "=&v"(c[5]), "=&v"(c[6]), "=&v"(c[7])
#define TIES(c) "+v"(c[0]), "+v"(c[1]), "+v"(c[2]), "+v"(c[3]), \
                "+v"(c[4]), "+v"(c[5]), "+v"(c[6]), "+v"(c[7])

__device__ inline unsigned char f32_to_e4m3(float f) {
  if (!(f > 0.f)) return 0;                  // negatives/NaN -> 0 (never expected)
  if (f >= 448.f) return 0x7e;               // clamp to max normal
  if (f < 0.015625f) {                       // subnormal: m = round(f*2^9)
    int m = (int)(f * 512.0f + 0.5f);
    return (unsigned char)(m > 7 ? 8 : m);   // m==8 promotes to 2^-6
  }
  union { float f; unsigned u; } v; v.f = f;
  int exp = (int)((v.u >> 23) & 0xffu) - 120;
  unsigned man = v.u & 0x7fffffu;
  unsigned m3 = man >> 20, rest = man & 0xfffffu;
  if (rest > 0x80000u || (rest == 0x80000u && (m3 & 1u))) ++m3;
  if (m3 == 8u) { m3 = 0u; ++exp; }
  if (exp >= 16) return 0x7e;
  return (unsigned char)((exp << 3) | m3);
}

__device__ inline float e4m3_to_f32(unsigned char x) {  // matches old k_final decode
  const int E = x >> 3, m = x & 7;
  return (E == 0) ? ldexpf((float)m, -9) : ldexpf(1.0f + 0.125f * (float)m, E - 7);
}

// Tiny counter-reset kernel (stream-ordered before k_all each iteration).
__global__ void k_zero(unsigned* __restrict__ bar) {
  if (threadIdx.x == 0)
    __hip_atomic_store(bar, 0u, __ATOMIC_RELAXED, __HIP_MEMORY_SCOPE_AGENT);
}

// THE kernel: phase A (sort) -> barrier -> phase B (gdst + initP1) -> barrier
// -> W-build -> main dataflow loop with pipelined poll + fused final reduction.
// Requires de-facto co-residency of all 128 blocks (grid <= CU count).
__global__ void __launch_bounds__(256, 1) k_all(
    const float* __restrict__ A, const float* __restrict__ fin,
    const int* __restrict__ xs, float* __restrict__ out,
    u64* __restrict__ PoutG, unsigned* __restrict__ order,
    unsigned* __restrict__ start, unsigned* __restrict__ count,
    unsigned* __restrict__ ppos, unsigned* __restrict__ gdst,
    unsigned* __restrict__ rdone, unsigned* __restrict__ bar, int depth) {
  __shared__ u64 Wl[8192];        // 64 KB fp8 B-fragments (sigma-compensated)
  __shared__ float tileA[8192];   // 32 KB, startup only
  __shared__ unsigned hist[SD], cur[SD];
  __shared__ unsigned sSt[TD], sCnt[TD];
  __shared__ unsigned cntA[TD];   // per-step wave-arrival counters (track mode)
  __shared__ float efin[QD];      // exp(final)
  __shared__ float red[64];       // final-step cross-wave row partials
  const int sid = blockIdx.x, tid = threadIdx.x;
  const int wave = tid >> 6, lane = tid & 63;
  const int quad = lane >> 4, lcol = lane & 15;
  const int pmask = depth - 1;
  const bool track = (depth < TD);

  // ---- phase A: counting sort for t=sid (block 0: ppos[0] identity) ----
  rdone[sid * 256 + tid] = 0u;
  if (sid == 0) {
    for (int b = tid; b < BD; b += 256)
      __hip_atomic_store(&ppos[b], (unsigned)b, __ATOMIC_RELAXED,
                         __HIP_MEMORY_SCOPE_AGENT);
  } else {
    const int t = sid;
    if (tid < SD) hist[tid] = 0u;
    __syncthreads();
    int sym[4];
    for (int r = 0; r < 4; ++r) {
      const int b = tid + 256 * r;
      sym[r] = xs[(size_t)b * TD + t];
      atomicAdd(&hist[sym[r]], 1u);
    }
    __syncthreads();
    if (tid == 0) {
      unsigned acc = 0;
      for (int s2 = 0; s2 < SD; ++s2) {
        cur[s2] = acc;
        __hip_atomic_store(&start[t * SD + s2], acc, __ATOMIC_RELAXED,
                           __HIP_MEMORY_SCOPE_AGENT);
        __hip_atomic_store(&count[t * SD + s2], hist[s2], __ATOMIC_RELAXED,
                           __HIP_MEMORY_SCOPE_AGENT);
        acc += hist[s2];
      }
    }
    __syncthreads();
    for (int r = 0; r < 4; ++r) {
      const int b = tid + 256 * r;
      const unsigned pos = atomicAdd(&cur[sym[r]], 1u);
      __hip_atomic_store(&order[(size_t)t * BD + pos], (unsigned)b,
                         __ATOMIC_RELAXED, __HIP_MEMORY_SCOPE_AGENT);
      __hip_atomic_store(&ppos[(size_t)t * BD + b], pos, __ATOMIC_RELAXED,
                         __HIP_MEMORY_SCOPE_AGENT);
    }
  }
  // manual grid barrier #1 (arrive after per-wave drain; target = SD)
  asm volatile("s_waitcnt vmcnt(0)" ::: "memory");
  __syncthreads();
  if (tid == 0) {
    __hip_atomic_fetch_add(bar, 1u, __ATOMIC_RELEASE, __HIP_MEMORY_SCOPE_AGENT);
    while (__hip_atomic_load(bar, __ATOMIC_ACQUIRE, __HIP_MEMORY_SCOPE_AGENT) < (unsigned)SD)
      __builtin_amdgcn_s_sleep(2);
  }
  __syncthreads();

  // ---- phase B: gdst[t][pos] = ppos[t+1][order[t][pos]] (t=1..TD-2) + initP1 ----
  if (sid >= 1 && sid < TD - 1) {
    const int t = sid;
    for (int pos = tid; pos < BD; pos += 256) {
      const unsigned d = ppos[(size_t)(t + 1) * BD + order[(size_t)t * BD + pos]];
      __hip_atomic_store(&gdst[(size_t)t * BD + pos], d, __ATOMIC_RELAXED,
                         __HIP_MEMORY_SCOPE_AGENT);
    }
  }
  for (int g = sid * 256 + tid; g < BD * 64; g += SD * 256) {  // P''_1 scatter
    const int b = g >> 6, w = g & 63;
    const int x0 = xs[(size_t)b * TD];
    unsigned p = 0u;
#pragma unroll
    for (int j = 0; j < 4; ++j) {
      float v = 0.5f * __expf(A[(size_t)x0 * QD + w * 4 + j]);
      p |= (unsigned)f32_to_e4m3(v) << (8 * j);
    }
    const unsigned pos = ppos[BD + b];  // step-1 layout position
    __hip_atomic_store(&PoutG[(size_t)(BD * 64) + (size_t)pos * 64 + w], (u64)p,
                       __ATOMIC_RELAXED, __HIP_MEMORY_SCOPE_AGENT);  // tag 0
  }
  // manual grid barrier #2 (target = 2*SD)
  asm volatile("s_waitcnt vmcnt(0)" ::: "memory");
  __syncthreads();
  if (tid == 0) {
    __hip_atomic_fetch_add(bar, 1u, __ATOMIC_RELEASE, __HIP_MEMORY_SCOPE_AGENT);
    while (__hip_atomic_load(bar, __ATOMIC_ACQUIRE, __HIP_MEMORY_SCOPE_AGENT) < 2u * (unsigned)SD)
      __builtin_amdgcn_s_sleep(2);
  }
  __syncthreads();

  // ---- startup: B[k][n_native] = exp(A[k][sid][p_out(n)])/4 ----
  for (int kb = 0; kb < 8; ++kb) {
    for (int r = 0; r < 32; ++r)
      tileA[r * QD + tid] = A[(size_t)(kb * 32 + r) * (SD * QD) + (size_t)sid * QD + tid];
    __syncthreads();
    for (int g = tid; g < 1024; g += 256) {
      const int n2 = g & 3, n = (g >> 2) & 15, q2 = (g >> 6) & 3, ntH = (g >> 8) & 3;
      const int nt = ntH * 4 + n2;
      const int col = ntH * 64 + n * 4 + n2;  // sigma compensation
      u64 w = 0ull;
#pragma unroll
      for (int j = 0; j < 8; ++j) {
        float v = __expf(tileA[(q2 * 8 + j) * QD + col]) * 0.25f;
        w |= (u64)f32_to_e4m3(v) << (8 * j);
      }
      Wl[(nt * 8 + kb) * 64 + q2 * 16 + n] = w;
    }
    __syncthreads();
  }
  for (int i = tid; i < TD; i += 256) {
    sCnt[i] = (i >= 1) ? count[i * SD + sid] : 0u;
    sSt[i]  = (i >= 1) ? start[i * SD + sid] : 0u;
    cntA[i] = 0u;
  }
  efin[tid] = __expf(fin[tid]);  // 256 threads cover QD exactly
  __syncthreads();

  // ---- main dataflow loop ----
  for (int t = 1; t < TD; ++t) {
    const unsigned cnt = sCnt[t], st = sSt[t];
    const int srcbuf = t & pmask, dstbuf = (t + 1) & pmask;
    const unsigned need = (unsigned)(t - 1);
    const u64* Psrc = PoutG + (size_t)srcbuf * (BD * 64);
    const bool dogate = (t >= depth);

    if (cnt) {
      const unsigned ntile = (cnt + 15u) >> 4;
      for (unsigned mt = 0; mt < ntile; ++mt) {
        // prefetch this tile's scatter destinations (hides under the spin)
        unsigned gd[4] = {0u, 0u, 0u, 0u};
        if (t < TD - 1) {
#pragma unroll
          for (int r = 0; r < 4; ++r) {
            const unsigned row = mt * 16u + (unsigned)(quad * 4 + r);
            const unsigned rc = (row < cnt) ? row : cnt - 1u;
            gd[r] = gdst[(size_t)t * BD + st + rc];
          }
        }

        const unsigned r0 = mt * 16u + (unsigned)(lane & 15);
        const unsigned ra = (r0 < cnt) ? r0 : cnt - 1u;  // clamped lanes not stored
        const u64 rowbase = (u64)(const void*)(Psrc + (size_t)(st + ra) * 64)
                            + (u64)((unsigned)quad * 16u);
        const bool gl = (dogate && mt == 0 && lane < 8);
        const bool gated = (track && dogate && mt == 0);

        // chunk kb = words {16*(kb>>1)+8*(kb&1)+quad*2, +1} = byte 64*kb+quad*16.
        uintx4 ch[8], cb[8];
        if (gated) {
          // fallback (depth<TD first tiles only): r14 single-set spin verbatim
          asm volatile(ISSUE8 : OUTS(ch) : "v"(rowbase) : "memory");
          unsigned spin = 0u;
          while (true) {
            asm volatile("s_waitcnt vmcnt(0)" : TIES(ch) :: "memory");
            __builtin_amdgcn_sched_barrier(0);
            bool ok = true;
#pragma unroll
            for (int kb = 0; kb < 8; ++kb)
              ok = ok && (ch[kb].y == need) && (ch[kb].w == need);
            if (gl)
              ok = ok && (__hip_atomic_load(rdone + (size_t)(t - depth + 1) * 256 + lane * 32,
                                            __ATOMIC_RELAXED, __HIP_MEMORY_SCOPE_AGENT) >= 16u);
            if (__ballot(ok) == ~0ull) break;
            asm volatile(ISSUE8 : OUTS(ch) : "v"(rowbase) : "memory");
            ++spin;
            if (spin > 8192u)      __builtin_amdgcn_s_sleep(64);
            else if (spin > 1024u) __builtin_amdgcn_s_sleep(16);
            else if (spin > 64u)   __builtin_amdgcn_s_sleep(4);
          }
        } else {
          // SAFE depth-2 pipelined poll: two named sets, >=1 in flight; check
          // only the vmcnt(8)-proven-complete set (vmcnt retires in issue
          // order); EVERY exit drains vmcnt(0) with both sets held live.
          bool winB = false;
          asm volatile(ISSUE8 : OUTS(ch) : "v"(rowbase) : "memory");
          asm volatile(ISSUE8 : OUTS(cb) : "v"(rowbase) : "memory");
          unsigned spin = 0u;
          while (true) {
            // --- A is oldest ---
            asm volatile("s_waitcnt vmcnt(8)" : TIES(ch) :: "memory");
            __builtin_amdgcn_sched_barrier(0);
            bool ok = true;
#pragma unroll
            for (int kb = 0; kb < 8; ++kb)
              ok = ok && (ch[kb].y == need) && (ch[kb].w == need);
            if (__ballot(ok) == ~0ull) {
              asm volatile("s_waitcnt vmcnt(0)" : TIES(ch), TIES(cb) :: "memory");
              break;
            }
            asm volatile(ISSUE8 : OUTS(ch) : "v"(rowbase) : "memory");
            ++spin;
            if (spin > 8192u)      __builtin_amdgcn_s_sleep(64);
            else if (spin > 1024u) __builtin_amdgcn_s_sleep(16);
            else if (spin > 64u)   __builtin_amdgcn_s_sleep(4);
            // --- B is oldest ---
            asm volatile("s_waitcnt vmcnt(8)" : TIES(cb) :: "memory");
            __builtin_amdgcn_sched_barrier(0);
            ok = true;
#pragma unroll
            for (int kb = 0; kb < 8; ++kb)
              ok = ok && (cb[kb].y == need) && (cb[kb].w == need);
            if (__ballot(ok) == ~0ull) {
              asm volatile("s_waitcnt vmcnt(0)" : TIES(ch), TIES(cb) :: "memory");
              winB = true;
              break;
            }
            asm volatile(ISSUE8 : OUTS(cb) : "v"(rowbase) : "memory");
            ++spin;
            if (spin > 8192u)      __builtin_amdgcn_s_sleep(64);
            else if (spin > 1024u) __builtin_amdgcn_s_sleep(16);
            else if (spin > 64u)   __builtin_amdgcn_s_sleep(4);
          }
          if (winB) {
#pragma unroll
            for (int i = 0; i < 8; ++i) ch[i] = cb[i];
          }
        }

        floatx4 acc[4] = {{0.f,0.f,0.f,0.f},{0.f,0.f,0.f,0.f},
                          {0.f,0.f,0.f,0.f},{0.f,0.f,0.f,0.f}};
#pragma unroll
        for (int kb = 0; kb < 8; ++kb) {
          const u64 a8 = (u64)ch[kb].x | ((u64)ch[kb].z << 32);
#pragma unroll
          for (int ntl = 0; ntl < 4; ++ntl) {
            const u64 bw = Wl[(((wave * 4 + ntl) * 8 + kb) * 64) + quad * 16 + lcol];
            acc[ntl] = __builtin_amdgcn_mfma_f32_16x16x32_fp8_fp8(
                (long)a8, (long)bw, acc[ntl], 0, 0, 0);
          }
        }

        if (t < TD - 1) {
          // tagged u64 stores scattered to next step's layout; word = wave*16+lcol
          u64* Pd = PoutG + (size_t)dstbuf * (BD * 64);
          const u64 tagw = ((u64)(unsigned)t) << 32;
#pragma unroll
          for (int r = 0; r < 4; ++r) {
            const unsigned row = mt * 16u + (unsigned)(quad * 4 + r);
            if (row < cnt) {
              const unsigned d =
                  (unsigned)f32_to_e4m3(acc[0][r] * 0.015625f) |
                  ((unsigned)f32_to_e4m3(acc[1][r] * 0.015625f) << 8) |
                  ((unsigned)f32_to_e4m3(acc[2][r] * 0.015625f) << 16) |
                  ((unsigned)f32_to_e4m3(acc[3][r] * 0.015625f) << 24);
              const u64 val = (u64)d | tagw;
              const u64 dptr = (u64)(void*)(Pd + (size_t)gd[r] * 64 + wave * 16 + lcol);
              asm volatile("global_store_dwordx2 %0, %1, off sc0 sc1"
                           :: "v"(dptr), "v"(val) : "memory");
            }
          }
        } else {
          // fused final: same e4m3 quantization roundtrip, * efin, reduce, log.
          // lane (wave,quad,lcol) col-tile ntl covers state (wave*16+lcol)*4+ntl
          // of tile row quad*4+r.
          const int sbase = (wave * 16 + lcol) * 4;
#pragma unroll
          for (int r = 0; r < 4; ++r) {
            float pv = 0.f;
#pragma unroll
            for (int ntl = 0; ntl < 4; ++ntl)
              pv += e4m3_to_f32(f32_to_e4m3(acc[ntl][r] * 0.015625f)) * efin[sbase + ntl];
            pv += __shfl_xor(pv, 1);   // sum over lcol (16 lanes)
            pv += __shfl_xor(pv, 2);
            pv += __shfl_xor(pv, 4);
            pv += __shfl_xor(pv, 8);
            if (lcol == 0) red[wave * 16 + quad * 4 + r] = pv;
          }
          __syncthreads();
          if (tid < 16) {
            const unsigned grow = mt * 16u + (unsigned)tid;
            if (grow < cnt) {
              const float tot = red[tid] + red[16 + tid] + red[32 + tid] + red[48 + tid];
              const unsigned b = order[(size_t)t * BD + st + grow];
              out[b] = logf(tot) + 1017.0f * 0.6931471805599453f;
            }
          }
          __syncthreads();
        }
      }
    }

    // arrive (gated-depth mode only): this wave's step-t source reads are
    // validated & in registers -> contribute to reads-done barrier
    if (track && lane == 0) {
      const unsigned old = atomicAdd(&cntA[t], 1u);
      if (old == 3u) {
        __hip_atomic_fetch_add(&rdone[(size_t)t * 256 + (sid & 7) * 32], 1u,
                               __ATOMIC_RELAXED, __HIP_MEMORY_SCOPE_AGENT);
      }
    }
  }
}

extern "C" void kernel_launch(void* const* d_in, const int* in_sizes, int n_in,
                              void* d_out, int out_size, void* d_ws, size_t ws_size,
                              hipStream_t stream) {
  const float* A    = (const float*)d_in[0];
  const float* init = (const float*)d_in[1];  // one-hot at state 0 (folded analytically)
  const float* fin  = (const float*)d_in[2];
  const int*   xs   = (const int*)d_in[3];
  float* out = (float*)d_out;
  (void)init;

  // Runtime parity depth: largest power of two in [8,128] whose PoutG + 2 MB aux
  // fits ws_size. depth=128 (66 MB) deletes the rdone gate/arrive entirely.
  const size_t AUX = (size_t)2048u << 10;           // 2 MB aux block
  const size_t PAR = (size_t)BD * 512u;             // 512 KB per parity
  int depth = 8;
  while (depth < TD && ws_size >= (size_t)(depth * 2) * PAR + AUX) depth *= 2;

  char* ws  = (char*)d_ws;
  u64* PoutG = (u64*)ws;                            // depth x 1024 x 512 B
  char* axp  = ws + (size_t)depth * PAR;
  unsigned* bar    = (unsigned*)axp;                // 4 B barrier counter
  unsigned* order  = (unsigned*)(axp + (256u << 10));   // 512 KB
  unsigned* start  = (unsigned*)(axp + (768u << 10));   // 64 KB
  unsigned* count  = (unsigned*)(axp + (832u << 10));   // 64 KB
  unsigned* ppos   = (unsigned*)(axp + (896u << 10));   // 512 KB
  unsigned* gdst   = (unsigned*)(axp + (1408u << 10));  // 512 KB
  unsigned* rdone  = (unsigned*)(axp + (1920u << 10));  // 128 KB  (total 2 MB)

  k_zero<<<dim3(1), dim3(64), 0, stream>>>(bar);
  k_all<<<dim3(SD), dim3(256), 0, stream>>>(A, fin, xs, out, PoutG, order, start,
                                            count, ppos, gdst, rdone, bar, depth);
}

// Round 16
// 644.983 us; speedup vs baseline: 1.2918x; 1.2918x over previous
//
#include <hip/hip_runtime.h>

#define QD 256   // states
#define SD 128   // symbols
#define BD 1024  // batch
#define TD 128   // time steps
// P rows stored as 64 SELF-VALIDATING u64 words: lo32 = 4 fp8 e4m3 payload bytes
// (stored byte p = P''[state p], identity stored space), hi32 = exact step tag.
// P''_1 = 2^-1 * P_1 (first transition folded); steps t=1..127:
// P'' <- (P'' @ exp(A)/4) * 2^-6 => *2^-8/step. out = log(sum P'' e^final) + 1017*ln2.
//
// THIS REVISION: REVERT to r14 (best verified: 645.6us total, 585us dispatch,
// absmax 0.0). r15's depth-2 pipelined poll regressed (793us dispatch): extra
// in-flight poll traffic pushed the coherence point past its congestion knee,
// inflating the very store-visibility latency being awaited. With r9 (traffic
// /4 -> flat) this brackets the design at its service-rate floor: ~4.3us/hop
// = pack 0.3 + visibility ~1 + detect ~0.7 + max-over-16-producers ~1, x127
// sequential hops. r14 structure: regular (graph-capturable) launches, manual
// agent-scope counter barrier for the two prologue phases, r8 hot loop (wide
// sc0/sc1 fused poll+fetch, check-before-reissue, producer-scatter/consumer-
// contiguous, depth-128 = no gate), tiered backoff, fused final reduction.

typedef float floatx4 __attribute__((ext_vector_type(4)));
typedef unsigned uintx4 __attribute__((ext_vector_type(4)));
typedef unsigned long long u64;

#define ISSUE8 \
  "global_load_dwordx4 %0, %8, off sc0 sc1\n\t" \
  "global_load_dwordx4 %1, %8, off offset:64 sc0 sc1\n\t" \
  "global_load_dwordx4 %2, %8, off offset:128 sc0 sc1\n\t" \
  "global_load_dwordx4 %3, %8, off offset:192 sc0 sc1\n\t" \
  "global_load_dwordx4 %4, %8, off offset:256 sc0 sc1\n\t" \
  "global_load_dwordx4 %5, %8, off offset:320 sc0 sc1\n\t" \
  "global_load_dwordx4 %6, %8, off offset:384 sc0 sc1\n\t" \
  "global_load_dwordx4 %7, %8, off offset:448 sc0 sc1"

__device__ inline unsigned char f32_to_e4m3(float f) {
  if (!(f > 0.f)) return 0;                  // negatives/NaN -> 0 (never expected)
  if (f >= 448.f) return 0x7e;               // clamp to max normal
  if (f < 0.015625f) {                       // subnormal: m = round(f*2^9)
    int m = (int)(f * 512.0f + 0.5f);
    return (unsigned char)(m > 7 ? 8 : m);   // m==8 promotes to 2^-6
  }
  union { float f; unsigned u; } v; v.f = f;
  int exp = (int)((v.u >> 23) & 0xffu) - 120;
  unsigned man = v.u & 0x7fffffu;
  unsigned m3 = man >> 20, rest = man & 0xfffffu;
  if (rest > 0x80000u || (rest == 0x80000u && (m3 & 1u))) ++m3;
  if (m3 == 8u) { m3 = 0u; ++exp; }
  if (exp >= 16) return 0x7e;
  return (unsigned char)((exp << 3) | m3);
}

__device__ inline float e4m3_to_f32(unsigned char x) {  // matches old k_final decode
  const int E = x >> 3, m = x & 7;
  return (E == 0) ? ldexpf((float)m, -9) : ldexpf(1.0f + 0.125f * (float)m, E - 7);
}

// Tiny counter-reset kernel (stream-ordered before k_all each iteration).
__global__ void k_zero(unsigned* __restrict__ bar) {
  if (threadIdx.x == 0)
    __hip_atomic_store(bar, 0u, __ATOMIC_RELAXED, __HIP_MEMORY_SCOPE_AGENT);
}

// THE kernel: phase A (sort) -> barrier -> phase B (gdst + initP1) -> barrier
// -> W-build -> main dataflow loop (r8 hot loop) with fused final reduction.
// Requires de-facto co-residency of all 128 blocks (grid <= CU count).
__global__ void __launch_bounds__(256, 1) k_all(
    const float* __restrict__ A, const float* __restrict__ fin,
    const int* __restrict__ xs, float* __restrict__ out,
    u64* __restrict__ PoutG, unsigned* __restrict__ order,
    unsigned* __restrict__ start, unsigned* __restrict__ count,
    unsigned* __restrict__ ppos, unsigned* __restrict__ gdst,
    unsigned* __restrict__ rdone, unsigned* __restrict__ bar, int depth) {
  __shared__ u64 Wl[8192];        // 64 KB fp8 B-fragments (sigma-compensated)
  __shared__ float tileA[8192];   // 32 KB, startup only
  __shared__ unsigned hist[SD], cur[SD];
  __shared__ unsigned sSt[TD], sCnt[TD];
  __shared__ unsigned cntA[TD];   // per-step wave-arrival counters (track mode)
  __shared__ float efin[QD];      // exp(final)
  __shared__ float red[64];       // final-step cross-wave row partials
  const int sid = blockIdx.x, tid = threadIdx.x;
  const int wave = tid >> 6, lane = tid & 63;
  const int quad = lane >> 4, lcol = lane & 15;
  const int pmask = depth - 1;
  const bool track = (depth < TD);

  // ---- phase A: counting sort for t=sid (block 0: ppos[0] identity) ----
  rdone[sid * 256 + tid] = 0u;
  if (sid == 0) {
    for (int b = tid; b < BD; b += 256)
      __hip_atomic_store(&ppos[b], (unsigned)b, __ATOMIC_RELAXED,
                         __HIP_MEMORY_SCOPE_AGENT);
  } else {
    const int t = sid;
    if (tid < SD) hist[tid] = 0u;
    __syncthreads();
    int sym[4];
    for (int r = 0; r < 4; ++r) {
      const int b = tid + 256 * r;
      sym[r] = xs[(size_t)b * TD + t];
      atomicAdd(&hist[sym[r]], 1u);
    }
    __syncthreads();
    if (tid == 0) {
      unsigned acc = 0;
      for (int s2 = 0; s2 < SD; ++s2) {
        cur[s2] = acc;
        __hip_atomic_store(&start[t * SD + s2], acc, __ATOMIC_RELAXED,
                           __HIP_MEMORY_SCOPE_AGENT);
        __hip_atomic_store(&count[t * SD + s2], hist[s2], __ATOMIC_RELAXED,
                           __HIP_MEMORY_SCOPE_AGENT);
        acc += hist[s2];
      }
    }
    __syncthreads();
    for (int r = 0; r < 4; ++r) {
      const int b = tid + 256 * r;
      const unsigned pos = atomicAdd(&cur[sym[r]], 1u);
      __hip_atomic_store(&order[(size_t)t * BD + pos], (unsigned)b,
                         __ATOMIC_RELAXED, __HIP_MEMORY_SCOPE_AGENT);
      __hip_atomic_store(&ppos[(size_t)t * BD + b], pos, __ATOMIC_RELAXED,
                         __HIP_MEMORY_SCOPE_AGENT);
    }
  }
  // manual grid barrier #1 (arrive after per-wave drain; target = SD)
  asm volatile("s_waitcnt vmcnt(0)" ::: "memory");
  __syncthreads();
  if (tid == 0) {
    __hip_atomic_fetch_add(bar, 1u, __ATOMIC_RELEASE, __HIP_MEMORY_SCOPE_AGENT);
    while (__hip_atomic_load(bar, __ATOMIC_ACQUIRE, __HIP_MEMORY_SCOPE_AGENT) < (unsigned)SD)
      __builtin_amdgcn_s_sleep(2);
  }
  __syncthreads();

  // ---- phase B: gdst[t][pos] = ppos[t+1][order[t][pos]] (t=1..TD-2) + initP1 ----
  if (sid >= 1 && sid < TD - 1) {
    const int t = sid;
    for (int pos = tid; pos < BD; pos += 256) {
      const unsigned d = ppos[(size_t)(t + 1) * BD + order[(size_t)t * BD + pos]];
      __hip_atomic_store(&gdst[(size_t)t * BD + pos], d, __ATOMIC_RELAXED,
                         __HIP_MEMORY_SCOPE_AGENT);
    }
  }
  for (int g = sid * 256 + tid; g < BD * 64; g += SD * 256) {  // P''_1 scatter
    const int b = g >> 6, w = g & 63;
    const int x0 = xs[(size_t)b * TD];
    unsigned p = 0u;
#pragma unroll
    for (int j = 0; j < 4; ++j) {
      float v = 0.5f * __expf(A[(size_t)x0 * QD + w * 4 + j]);
      p |= (unsigned)f32_to_e4m3(v) << (8 * j);
    }
    const unsigned pos = ppos[BD + b];  // step-1 layout position
    __hip_atomic_store(&PoutG[(size_t)(BD * 64) + (size_t)pos * 64 + w], (u64)p,
                       __ATOMIC_RELAXED, __HIP_MEMORY_SCOPE_AGENT);  // tag 0
  }
  // manual grid barrier #2 (target = 2*SD)
  asm volatile("s_waitcnt vmcnt(0)" ::: "memory");
  __syncthreads();
  if (tid == 0) {
    __hip_atomic_fetch_add(bar, 1u, __ATOMIC_RELEASE, __HIP_MEMORY_SCOPE_AGENT);
    while (__hip_atomic_load(bar, __ATOMIC_ACQUIRE, __HIP_MEMORY_SCOPE_AGENT) < 2u * (unsigned)SD)
      __builtin_amdgcn_s_sleep(2);
  }
  __syncthreads();

  // ---- startup: B[k][n_native] = exp(A[k][sid][p_out(n)])/4 ----
  for (int kb = 0; kb < 8; ++kb) {
    for (int r = 0; r < 32; ++r)
      tileA[r * QD + tid] = A[(size_t)(kb * 32 + r) * (SD * QD) + (size_t)sid * QD + tid];
    __syncthreads();
    for (int g = tid; g < 1024; g += 256) {
      const int n2 = g & 3, n = (g >> 2) & 15, q2 = (g >> 6) & 3, ntH = (g >> 8) & 3;
      const int nt = ntH * 4 + n2;
      const int col = ntH * 64 + n * 4 + n2;  // sigma compensation
      u64 w = 0ull;
#pragma unroll
      for (int j = 0; j < 8; ++j) {
        float v = __expf(tileA[(q2 * 8 + j) * QD + col]) * 0.25f;
        w |= (u64)f32_to_e4m3(v) << (8 * j);
      }
      Wl[(nt * 8 + kb) * 64 + q2 * 16 + n] = w;
    }
    __syncthreads();
  }
  for (int i = tid; i < TD; i += 256) {
    sCnt[i] = (i >= 1) ? count[i * SD + sid] : 0u;
    sSt[i]  = (i >= 1) ? start[i * SD + sid] : 0u;
    cntA[i] = 0u;
  }
  efin[tid] = __expf(fin[tid]);  // 256 threads cover QD exactly
  __syncthreads();

  // ---- main dataflow loop (r8 hot loop, unchanged for t < TD-1) ----
  for (int t = 1; t < TD; ++t) {
    const unsigned cnt = sCnt[t], st = sSt[t];
    const int srcbuf = t & pmask, dstbuf = (t + 1) & pmask;
    const unsigned need = (unsigned)(t - 1);
    const u64* Psrc = PoutG + (size_t)srcbuf * (BD * 64);
    const bool dogate = (t >= depth);

    if (cnt) {
      const unsigned ntile = (cnt + 15u) >> 4;
      for (unsigned mt = 0; mt < ntile; ++mt) {
        // prefetch this tile's scatter destinations (hides under the spin)
        unsigned gd[4] = {0u, 0u, 0u, 0u};
        if (t < TD - 1) {
#pragma unroll
          for (int r = 0; r < 4; ++r) {
            const unsigned row = mt * 16u + (unsigned)(quad * 4 + r);
            const unsigned rc = (row < cnt) ? row : cnt - 1u;
            gd[r] = gdst[(size_t)t * BD + st + rc];
          }
        }

        const unsigned r0 = mt * 16u + (unsigned)(lane & 15);
        const unsigned ra = (r0 < cnt) ? r0 : cnt - 1u;  // clamped lanes not stored
        const u64 rowbase = (u64)(const void*)(Psrc + (size_t)(st + ra) * 64)
                            + (u64)((unsigned)quad * 16u);
        const bool gl = (dogate && mt == 0 && lane < 8);

        // fused poll+fetch: check BEFORE reissue -> exits with vmcnt==0 (safe).
        // chunk kb = words {16*(kb>>1)+8*(kb&1)+quad*2, +1} = byte 64*kb+quad*16.
        uintx4 ch[8];
        asm volatile(ISSUE8
            : "=&v"(ch[0]), "=&v"(ch[1]), "=&v"(ch[2]), "=&v"(ch[3]),
              "=&v"(ch[4]), "=&v"(ch[5]), "=&v"(ch[6]), "=&v"(ch[7])
            : "v"(rowbase)
            : "memory");
        unsigned spin = 0u;
        while (true) {
          asm volatile("s_waitcnt vmcnt(0)"
              : "+v"(ch[0]), "+v"(ch[1]), "+v"(ch[2]), "+v"(ch[3]),
                "+v"(ch[4]), "+v"(ch[5]), "+v"(ch[6]), "+v"(ch[7])
              :: "memory");
          __builtin_amdgcn_sched_barrier(0);
          bool ok = true;
#pragma unroll
          for (int kb = 0; kb < 8; ++kb)
            ok = ok && (ch[kb].y == need) && (ch[kb].w == need);
          if (gl)
            ok = ok && (__hip_atomic_load(rdone + (size_t)(t - depth + 1) * 256 + lane * 32,
                                          __ATOMIC_RELAXED, __HIP_MEMORY_SCOPE_AGENT) >= 16u);
          if (__ballot(ok) == ~0ull) break;
          asm volatile(ISSUE8
              : "=&v"(ch[0]), "=&v"(ch[1]), "=&v"(ch[2]), "=&v"(ch[3]),
                "=&v"(ch[4]), "=&v"(ch[5]), "=&v"(ch[6]), "=&v"(ch[7])
              : "v"(rowbase)
              : "memory");
          // tiered backoff: common path (<64 spins) untouched; long waits shed
          // load fast to break poll-storm congestion.
          ++spin;
          if (spin > 8192u)      __builtin_amdgcn_s_sleep(64);
          else if (spin > 1024u) __builtin_amdgcn_s_sleep(16);
          else if (spin > 64u)   __builtin_amdgcn_s_sleep(4);
        }

        floatx4 acc[4] = {{0.f,0.f,0.f,0.f},{0.f,0.f,0.f,0.f},
                          {0.f,0.f,0.f,0.f},{0.f,0.f,0.f,0.f}};
#pragma unroll
        for (int kb = 0; kb < 8; ++kb) {
          const u64 a8 = (u64)ch[kb].x | ((u64)ch[kb].z << 32);
#pragma unroll
          for (int ntl = 0; ntl < 4; ++ntl) {
            const u64 bw = Wl[(((wave * 4 + ntl) * 8 + kb) * 64) + quad * 16 + lcol];
            acc[ntl] = __builtin_amdgcn_mfma_f32_16x16x32_fp8_fp8(
                (long)a8, (long)bw, acc[ntl], 0, 0, 0);
          }
        }

        if (t < TD - 1) {
          // tagged u64 stores scattered to next step's layout; word = wave*16+lcol
          u64* Pd = PoutG + (size_t)dstbuf * (BD * 64);
          const u64 tagw = ((u64)(unsigned)t) << 32;
#pragma unroll
          for (int r = 0; r < 4; ++r) {
            const unsigned row = mt * 16u + (unsigned)(quad * 4 + r);
            if (row < cnt) {
              const unsigned d =
                  (unsigned)f32_to_e4m3(acc[0][r] * 0.015625f) |
                  ((unsigned)f32_to_e4m3(acc[1][r] * 0.015625f) << 8) |
                  ((unsigned)f32_to_e4m3(acc[2][r] * 0.015625f) << 16) |
                  ((unsigned)f32_to_e4m3(acc[3][r] * 0.015625f) << 24);
              const u64 val = (u64)d | tagw;
              const u64 dptr = (u64)(void*)(Pd + (size_t)gd[r] * 64 + wave * 16 + lcol);
              asm volatile("global_store_dwordx2 %0, %1, off sc0 sc1"
                           :: "v"(dptr), "v"(val) : "memory");
            }
          }
        } else {
          // fused final: same e4m3 quantization roundtrip, * efin, reduce, log.
          // lane (wave,quad,lcol) col-tile ntl covers state (wave*16+lcol)*4+ntl
          // of tile row quad*4+r.
          const int sbase = (wave * 16 + lcol) * 4;
#pragma unroll
          for (int r = 0; r < 4; ++r) {
            float pv = 0.f;
#pragma unroll
            for (int ntl = 0; ntl < 4; ++ntl)
              pv += e4m3_to_f32(f32_to_e4m3(acc[ntl][r] * 0.015625f)) * efin[sbase + ntl];
            pv += __shfl_xor(pv, 1);   // sum over lcol (16 lanes)
            pv += __shfl_xor(pv, 2);
            pv += __shfl_xor(pv, 4);
            pv += __shfl_xor(pv, 8);
            if (lcol == 0) red[wave * 16 + quad * 4 + r] = pv;
          }
          __syncthreads();
          if (tid < 16) {
            const unsigned grow = mt * 16u + (unsigned)tid;
            if (grow < cnt) {
              const float tot = red[tid] + red[16 + tid] + red[32 + tid] + red[48 + tid];
              const unsigned b = order[(size_t)t * BD + st + grow];
              out[b] = logf(tot) + 1017.0f * 0.6931471805599453f;
            }
          }
          __syncthreads();
        }
      }
    }

    // arrive (gated-depth mode only): this wave's step-t source reads are
    // validated & in registers -> contribute to reads-done barrier
    if (track && lane == 0) {
      const unsigned old = atomicAdd(&cntA[t], 1u);
      if (old == 3u) {
        __hip_atomic_fetch_add(&rdone[(size_t)t * 256 + (sid & 7) * 32], 1u,
                               __ATOMIC_RELAXED, __HIP_MEMORY_SCOPE_AGENT);
      }
    }
  }
}

extern "C" void kernel_launch(void* const* d_in, const int* in_sizes, int n_in,
                              void* d_out, int out_size, void* d_ws, size_t ws_size,
                              hipStream_t stream) {
  const float* A    = (const float*)d_in[0];
  const float* init = (const float*)d_in[1];  // one-hot at state 0 (folded analytically)
  const float* fin  = (const float*)d_in[2];
  const int*   xs   = (const int*)d_in[3];
  float* out = (float*)d_out;
  (void)init;

  // Runtime parity depth: largest power of two in [8,128] whose PoutG + 2 MB aux
  // fits ws_size. depth=128 (66 MB) deletes the rdone gate/arrive entirely.
  const size_t AUX = (size_t)2048u << 10;           // 2 MB aux block
  const size_t PAR = (size_t)BD * 512u;             // 512 KB per parity
  int depth = 8;
  while (depth < TD && ws_size >= (size_t)(depth * 2) * PAR + AUX) depth *= 2;

  char* ws  = (char*)d_ws;
  u64* PoutG = (u64*)ws;                            // depth x 1024 x 512 B
  char* axp  = ws + (size_t)depth * PAR;
  unsigned* bar    = (unsigned*)axp;                // 4 B barrier counter
  unsigned* order  = (unsigned*)(axp + (256u << 10));   // 512 KB
  unsigned* start  = (unsigned*)(axp + (768u << 10));   // 64 KB
  unsigned* count  = (unsigned*)(axp + (832u << 10));   // 64 KB
  unsigned* ppos   = (unsigned*)(axp + (896u << 10));   // 512 KB
  unsigned* gdst   = (unsigned*)(axp + (1408u << 10));  // 512 KB
  unsigned* rdone  = (unsigned*)(axp + (1920u << 10));  // 128 KB  (total 2 MB)

  k_zero<<<dim3(1), dim3(64), 0, stream>>>(bar);
  k_all<<<dim3(SD), dim3(256), 0, stream>>>(A, fin, xs, out, PoutG, order, start,
                                            count, ppos, gdst, rdone, bar, depth);
}